// Round 16
// baseline (66.814 us; speedup 1.0000x reference)
//
#include <hip/hip_runtime.h>
#include <stdint.h>

// Problem constants
#define B_N   32768
#define D_IN  35
#define NJ    12
#define NQ    7
#define NO    5
#define QO    35
#define TILE  16                   // samples per block (16 -> 2x independent blocks)
#define TPJ   256                  // perm region: 4096 samples/judge cap
#define CAPJ  4096
#define MAXT  2060                 // >= max possible live tiles (2048+12)

typedef __bf16  v8bf  __attribute__((ext_vector_type(8)));
typedef float   f32x4 __attribute__((ext_vector_type(4)));

__device__ __forceinline__ unsigned short f2bf(float f) {
    unsigned int u = __builtin_bit_cast(unsigned int, f);
    u += 0x7FFFu + ((u >> 16) & 1u);   // round-to-nearest-even
    return (unsigned short)(u >> 16);
}
__device__ __forceinline__ unsigned int pack2(float a, float b) {
    return (unsigned int)f2bf(a) | ((unsigned int)f2bf(b) << 16);
}

// ---------------------------------------------------------------------------
// Kernel 1: weight combine (grid-stride) + scatter (blocks 0..127 each own a
// 256-sample slice of ids -> fixed per-judge perm regions). No serial tail.
// cursor[] pre-zeroed by a 48B memset; final values = per-judge counts.
// w1c: [12][256][64] (k>=35 zero)   w2c: [12][256][256]   vc: [12][48][256]
// ---------------------------------------------------------------------------
__global__ void k_prep(const int* __restrict__ ids,
                       const float* __restrict__ W1_w, const float* __restrict__ W1_b,
                       const float* __restrict__ W2_w, const float* __restrict__ W2_b,
                       const float* __restrict__ W1a_w, const float* __restrict__ W1a_b,
                       const float* __restrict__ W2a_w, const float* __restrict__ W2a_b,
                       const float* __restrict__ V_w,  const float* __restrict__ V_b,
                       const float* __restrict__ Va_w, const float* __restrict__ Va_b,
                       unsigned short* __restrict__ w1c, unsigned short* __restrict__ w2c,
                       unsigned short* __restrict__ vc,
                       float* __restrict__ bias1, float* __restrict__ bias2,
                       float* __restrict__ biasv,
                       int* __restrict__ cursor, int* __restrict__ perm)
{
    const int tid = blockIdx.x * blockDim.x + threadIdx.x;
    const int nth = gridDim.x * blockDim.x;

    // ---- scatter: blocks 0..127, one 256-id slice each ----
    if (blockIdx.x < B_N / 256) {
        __shared__ int lh[NJ], lb[NJ];
        const int lt = threadIdx.x;
        const int s0 = blockIdx.x * 256;
        if (lt < NJ) lh[lt] = 0;
        __syncthreads();
        int id = ids[s0 + lt];
        int rank = atomicAdd(&lh[id], 1);
        __syncthreads();
        if (lt < NJ)
            lb[lt] = lh[lt] ? atomicAdd(&cursor[lt], lh[lt]) : 0;
        __syncthreads();
        int pos = lb[id] + rank;
        if (pos < CAPJ) perm[id * CAPJ + pos] = s0 + lt;
    }

    // ---- weight combine (grid-stride over all blocks) ----
    // w2c: 12*256*64 quads
    for (int q = tid; q < NJ * 256 * 64; q += nth) {
        int k4 = (q & 63) << 2, h = (q >> 6) & 255, jj = q >> 14;
        const float* a = &W2_w[h * 257 + k4];
        const float* b = &W2a_w[(jj * 256 + h) * 257 + k4];
        ushort4 o;
        o.x = f2bf(a[0] + b[0]); o.y = f2bf(a[1] + b[1]);
        o.z = f2bf(a[2] + b[2]); o.w = f2bf(a[3] + b[3]);
        *(ushort4*)&w2c[(size_t)q << 2] = o;
    }
    // w1c: 12*256*16 quads (k padded to 64)
    for (int q = tid; q < NJ * 256 * 16; q += nth) {
        int k4 = (q & 15) << 2, h = (q >> 4) & 255, jj = q >> 12;
        ushort4 o;
        float v[4];
#pragma unroll
        for (int e = 0; e < 4; ++e) {
            int k = k4 + e;
            v[e] = (k < D_IN) ? (W1_w[h * 36 + k] + W1a_w[(jj * 256 + h) * 36 + k]) : 0.f;
        }
        o.x = f2bf(v[0]); o.y = f2bf(v[1]); o.z = f2bf(v[2]); o.w = f2bf(v[3]);
        *(ushort4*)&w1c[(size_t)q << 2] = o;
    }
    // vc: 12*48*64 quads
    for (int q = tid; q < NJ * 48 * 64; q += nth) {
        int k4 = (q & 63) << 2, qo = (q >> 6) % 48, jj = q / (48 * 64);
        ushort4 o;
        if (qo < QO) {
            const float* a = &V_w[qo * 257 + k4];
            const float* b = &Va_w[(jj * QO + qo) * 257 + k4];
            o.x = f2bf(a[0] + b[0]); o.y = f2bf(a[1] + b[1]);
            o.z = f2bf(a[2] + b[2]); o.w = f2bf(a[3] + b[3]);
        } else {
            o.x = o.y = o.z = o.w = 0;
        }
        *(ushort4*)&vc[(size_t)q << 2] = o;
    }
    // biases (fold ones-column)
    for (int i = tid; i < NJ * 256; i += nth) {
        int h = i & 255, jj = i >> 8;
        bias1[i] = W1_w[h * 36 + 35] + W1a_w[(jj * 256 + h) * 36 + 35] + W1_b[h] + W1a_b[i];
        bias2[i] = W2_w[h * 257 + 256] + W2a_w[(jj * 256 + h) * 257 + 256] + W2_b[h] + W2a_b[i];
    }
    for (int i = tid; i < NJ * 48; i += nth) {
        int qo = i % 48, jj = i / 48;
        float v = 0.f;
        if (qo < QO) v = V_w[qo * 257 + 256] + Va_w[(jj * QO + qo) * 257 + 256]
                       + V_b[qo] + Va_b[jj * QO + qo];
        biasv[i] = v;
    }
}

// ---------------------------------------------------------------------------
// Kernel 2: fused MLP — 16-sample blocks, 4 waves of 64 N-rows (no sample
// subtile dim). LDS ~11 KB -> 8 blocks/CU (thread-capped, 32 waves/CU);
// ~2054 live blocks ~= 8 available/CU = 2x the independent scheduling units
// of the 32-sample variant. 6 barriers; depth-1 weight prefetch across each
// barrier. Compact tile dispatch from counts[12]; m204 XCD swizzle over nt.
// MFMA 16x16x32 bf16 layouts:
//   A: lane holds A[lane&15][(lane>>4)*8+e]      (weights = A, rows)
//   B: lane holds B[(lane>>4)*8+e][lane&15]      (samples = B, cols)
//   D: col=lane&15 (sample), row=(lane>>4)*4+r   (output row)
// ---------------------------------------------------------------------------
__global__ __launch_bounds__(256, 4) void k_main(
    const float* __restrict__ x, float* __restrict__ out,
    const int* __restrict__ perm, const int* __restrict__ counts,
    const unsigned short* __restrict__ w1c, const unsigned short* __restrict__ w2c,
    const unsigned short* __restrict__ vc,
    const float* __restrict__ bias1, const float* __restrict__ bias2,
    const float* __restrict__ biasv)
{
    __shared__ __align__(16) unsigned short s_z1[TILE][264];   // z1, then z2
    __shared__ __align__(16) union {
        unsigned short xb[TILE][72];   // bf16 input tile (dead after layer 1)
        float          lg[TILE][40];   // logits (born at heads)
    } s_u;
    __shared__ int s_rows[TILE];

    const int bid = blockIdx.x;

    // ---- compact tile map from counts (uniform scalar ops, no arrays) ----
    int nt = 0;
#pragma unroll
    for (int jj = 0; jj < NJ; ++jj) nt += (counts[jj] + TILE - 1) >> 4;
    if (bid >= nt) return;

    // m204 bijective XCD swizzle over the live-tile space.
    const int q8 = nt >> 3, r8 = nt & 7;
    const int xcd = bid & 7, idx = bid >> 3;
    const int lbid = (xcd < r8 ? xcd * (q8 + 1) : r8 * (q8 + 1) + (xcd - r8) * q8) + idx;

    int j = 0, tb_j = 0, cj = 0, pacc = 0;
#pragma unroll
    for (int jj = 0; jj < NJ; ++jj) {
        int c = counts[jj];
        if (lbid >= pacc) { j = jj; tb_j = pacc; cj = c; }   // last satisfied wins
        pacc += (c + TILE - 1) >> 4;
    }
    if (cj > CAPJ) cj = CAPJ;          // insurance vs perm region overflow
    const int ts = (lbid - tb_j) << 4; // tile start within judge region

    const int tid  = threadIdx.x;
    const int lane = tid & 63;
    const int wave = tid >> 6;
    const int l16  = lane & 15;
    const int lk   = lane >> 4;

    // ---- prefetch ALL of this wave's layer-1 A fragments (32 VGPR) ----
    const unsigned short* w1p = w1c + ((size_t)j << 14) + (size_t)(wave * 64) * 64;
    v8bf w1a0[4], w1a1[4];
#pragma unroll
    for (int t = 0; t < 4; ++t) {
        const unsigned short* rp = w1p + (t * 16 + l16) * 64;
        w1a0[t] = *(const v8bf*)&rp[lk * 8];
        w1a1[t] = *(const v8bf*)&rp[32 + lk * 8];
    }

    if (tid < TILE)
        s_rows[tid] = (ts + tid < cj) ? perm[j * CAPJ + ts + tid] : -1;
    for (int i = tid; i < TILE * 36; i += 256) ((unsigned int*)s_u.xb)[i] = 0u;
    __syncthreads();                                   // (a) rows+zero ready

    for (int i = tid; i < TILE * D_IN; i += 256) {
        int s = i / D_IN, k = i - s * D_IN;
        int r = s_rows[s];
        s_u.xb[s][k] = f2bf(r >= 0 ? x[(size_t)r * D_IN + k] : 0.f);
    }
    __syncthreads();                                   // (b) xb ready

    const f32x4 vz = {0.f, 0.f, 0.f, 0.f};

    // ---- layer 1: z1[s][h] = relu(W1c[h]·xb[s] + b1[h]), wave owns 64 h ----
    {
        v8bf b1_0 = *(const v8bf*)&s_u.xb[l16][lk * 8];
        v8bf b1_1 = *(const v8bf*)&s_u.xb[l16][32 + lk * 8];
        f32x4 acc[4];
#pragma unroll
        for (int t = 0; t < 4; ++t) acc[t] = vz;
#pragma unroll
        for (int t = 0; t < 4; ++t) {
            acc[t] = __builtin_amdgcn_mfma_f32_16x16x32_bf16(w1a0[t], b1_0, acc[t], 0, 0, 0);
            acc[t] = __builtin_amdgcn_mfma_f32_16x16x32_bf16(w1a1[t], b1_1, acc[t], 0, 0, 0);
        }
        // prefetch layer-2 hc=0 A fragments before the barrier (16 VGPR)
        const unsigned short* w2p = w2c + ((size_t)j << 16) + (size_t)(wave * 64) * 256;
        v8bf a2pre[4];
#pragma unroll
        for (int gt = 0; gt < 4; ++gt)
            a2pre[gt] = *(const v8bf*)&w2p[(gt * 16 + l16) * 256 + lk * 8];

#pragma unroll
        for (int t = 0; t < 4; ++t) {
            f32x4 bz = *(const f32x4*)&bias1[j * 256 + wave * 64 + t * 16 + lk * 4];
            float v0 = acc[t][0] + bz[0], v1 = acc[t][1] + bz[1];
            float v2 = acc[t][2] + bz[2], v3 = acc[t][3] + bz[3];
            v0 = v0 > 0.f ? v0 : 0.f; v1 = v1 > 0.f ? v1 : 0.f;
            v2 = v2 > 0.f ? v2 : 0.f; v3 = v3 > 0.f ? v3 : 0.f;
            uint2 pk; pk.x = pack2(v0, v1); pk.y = pack2(v2, v3);
            *(uint2*)&s_z1[l16][wave * 64 + t * 16 + lk * 4] = pk;
        }
        __syncthreads();                               // (c) z1 ready

        // ---- layer 2: z2 = relu(z1 @ W2c^T + b2), wave owns 64 g-rows ----
        f32x4 acc2[4];
#pragma unroll
        for (int gt = 0; gt < 4; ++gt) acc2[gt] = vz;
        {   // hc = 0 (prefetched A)
            v8bf bb = *(const v8bf*)&s_z1[l16][lk * 8];
#pragma unroll
            for (int gt = 0; gt < 4; ++gt)
                acc2[gt] = __builtin_amdgcn_mfma_f32_16x16x32_bf16(a2pre[gt], bb, acc2[gt], 0, 0, 0);
        }
#pragma unroll 2
        for (int hc = 1; hc < 8; ++hc) {
            v8bf bb = *(const v8bf*)&s_z1[l16][hc * 32 + lk * 8];
#pragma unroll
            for (int gt = 0; gt < 4; ++gt) {
                v8bf a = *(const v8bf*)&w2p[(gt * 16 + l16) * 256 + hc * 32 + lk * 8];
                acc2[gt] = __builtin_amdgcn_mfma_f32_16x16x32_bf16(a, bb, acc2[gt], 0, 0, 0);
            }
        }
        // prefetch heads gc=0 A fragment (in flight across the next barrier)
        const unsigned short* vp = vc + (size_t)j * 12288 + (size_t)(wave * 16) * 256;
        v8bf a3pre;
        if (wave < 3) a3pre = *(const v8bf*)&vp[l16 * 256 + lk * 8];

        __syncthreads();                               // (d) z1 reads drained
#pragma unroll
        for (int gt = 0; gt < 4; ++gt) {
            f32x4 bz = *(const f32x4*)&bias2[j * 256 + wave * 64 + gt * 16 + lk * 4];
            float v0 = acc2[gt][0] + bz[0], v1 = acc2[gt][1] + bz[1];
            float v2 = acc2[gt][2] + bz[2], v3 = acc2[gt][3] + bz[3];
            v0 = v0 > 0.f ? v0 : 0.f; v1 = v1 > 0.f ? v1 : 0.f;
            v2 = v2 > 0.f ? v2 : 0.f; v3 = v3 > 0.f ? v3 : 0.f;
            uint2 pk; pk.x = pack2(v0, v1); pk.y = pack2(v2, v3);
            *(uint2*)&s_z1[l16][wave * 64 + gt * 16 + lk * 4] = pk;
        }
        __syncthreads();                               // (e) z2 ready

        // ---- heads: logits[s][qo] = Vc[qo]·z2[s] + bv[qo]; waves 0..2 ----
        if (wave < 3) {
            f32x4 av = vz;
            {   // gc = 0 (prefetched A)
                v8bf bb = *(const v8bf*)&s_z1[l16][lk * 8];
                av = __builtin_amdgcn_mfma_f32_16x16x32_bf16(a3pre, bb, av, 0, 0, 0);
            }
#pragma unroll 4
            for (int gc = 1; gc < 8; ++gc) {
                v8bf bb = *(const v8bf*)&s_z1[l16][gc * 32 + lk * 8];
                v8bf a = *(const v8bf*)&vp[l16 * 256 + gc * 32 + lk * 8];
                av = __builtin_amdgcn_mfma_f32_16x16x32_bf16(a, bb, av, 0, 0, 0);
            }
            int qb = wave * 16 + lk * 4;
            if (qb < 36) {   // rows >= 35 never read by softmax
                f32x4 bz = *(const f32x4*)&biasv[j * 48 + qb];
                f32x4 v = av + bz;
                *(f32x4*)&s_u.lg[l16][qb] = v;
            }
        }
    }
    __syncthreads();                                   // (f) logits ready

    // ---- softmax over O=5 per (s,q), write out ----
    if (tid < TILE * NQ) {
        int s = tid / NQ, qq = tid - s * NQ;
        int r = s_rows[s];
        if (r >= 0) {
            float l[NO], mx = -1e30f;
#pragma unroll
            for (int o = 0; o < NO; ++o) {
                l[o] = s_u.lg[s][qq * NO + o];
                mx = l[o] > mx ? l[o] : mx;
            }
            float sum = 0.f, e[NO];
#pragma unroll
            for (int o = 0; o < NO; ++o) { e[o] = __expf(l[o] - mx); sum += e[o]; }
            float inv = 1.f / sum;
            float* op = out + (size_t)r * QO + qq * NO;
#pragma unroll
            for (int o = 0; o < NO; ++o) op[o] = e[o] * inv;
        }
    }
}

// ---------------------------------------------------------------------------
extern "C" void kernel_launch(void* const* d_in, const int* in_sizes, int n_in,
                              void* d_out, int out_size, void* d_ws, size_t ws_size,
                              hipStream_t stream)
{
    const float* x     = (const float*)d_in[0];
    const int*   ids   = (const int*)d_in[1];
    const float* W1_w  = (const float*)d_in[2];
    const float* W1_b  = (const float*)d_in[3];
    const float* W2_w  = (const float*)d_in[4];
    const float* W2_b  = (const float*)d_in[5];
    const float* W1a_w = (const float*)d_in[6];
    const float* W1a_b = (const float*)d_in[7];
    const float* W2a_w = (const float*)d_in[8];
    const float* W2a_b = (const float*)d_in[9];
    const float* V_w   = (const float*)d_in[10];
    const float* V_b   = (const float*)d_in[11];
    const float* Va_w  = (const float*)d_in[12];
    const float* Va_b  = (const float*)d_in[13];
    float* out = (float*)d_out;

    char* ws = (char*)d_ws;
    size_t off = 0;
    auto take = [&](size_t nbytes) -> void* {
        void* p = ws + off;
        off = (off + nbytes + 255) & ~(size_t)255;
        return p;
    };
    unsigned short* w1c = (unsigned short*)take((size_t)NJ * 256 * 64 * 2);
    unsigned short* w2c = (unsigned short*)take((size_t)NJ * 256 * 256 * 2);
    unsigned short* vc  = (unsigned short*)take((size_t)NJ * 48 * 256 * 2);
    float* bias1        = (float*)take((size_t)NJ * 256 * 4);
    float* bias2        = (float*)take((size_t)NJ * 256 * 4);
    float* biasv        = (float*)take((size_t)NJ * 48 * 4);
    int* cursor         = (int*)take(NJ * 4);
    int* perm           = (int*)take((size_t)NJ * CAPJ * 4);

    hipMemsetAsync(cursor, 0, NJ * sizeof(int), stream);   // 48 B, trivial
    k_prep<<<768, 256, 0, stream>>>(ids, W1_w, W1_b, W2_w, W2_b, W1a_w, W1a_b,
                                    W2a_w, W2a_b, V_w, V_b, Va_w, Va_b,
                                    w1c, w2c, vc, bias1, bias2, biasv,
                                    cursor, perm);
    k_main<<<MAXT, 256, 0, stream>>>(x, out, perm, cursor,
                                     w1c, w2c, vc, bias1, bias2, biasv);
}

// Round 17
// 46.636 us; speedup vs baseline: 1.4327x; 1.4327x over previous
//
#include <hip/hip_runtime.h>
#include <stdint.h>

// Problem constants
#define B_N   32768
#define D_IN  35
#define NJ    12
#define NQ    7
#define NO    5
#define QO    35
#define TILE  32
#define TPJ   128                  // perm region: 4096 samples/judge cap (~27 sigma)
#define CAPJ  (TPJ * TILE)
#define MAXT  1040                 // >= max possible live tiles (1035)

typedef __bf16  v8bf  __attribute__((ext_vector_type(8)));
typedef float   f32x4 __attribute__((ext_vector_type(4)));

__device__ __forceinline__ unsigned short f2bf(float f) {
    unsigned int u = __builtin_bit_cast(unsigned int, f);
    u += 0x7FFFu + ((u >> 16) & 1u);   // round-to-nearest-even
    return (unsigned short)(u >> 16);
}
__device__ __forceinline__ unsigned int pack2(float a, float b) {
    return (unsigned int)f2bf(a) | ((unsigned int)f2bf(b) << 16);
}

// ---------------------------------------------------------------------------
// Kernel 1: weight combine (grid-stride) + scatter (blocks 0..127 each own a
// 256-sample slice of ids -> fixed per-judge perm regions). No serial tail.
// cursor[] pre-zeroed by a 48B memset; final values = per-judge counts.
// w1c: [12][256][64] (k>=35 zero)   w2c: [12][256][256]   vc: [12][48][256]
// ---------------------------------------------------------------------------
__global__ void k_prep(const int* __restrict__ ids,
                       const float* __restrict__ W1_w, const float* __restrict__ W1_b,
                       const float* __restrict__ W2_w, const float* __restrict__ W2_b,
                       const float* __restrict__ W1a_w, const float* __restrict__ W1a_b,
                       const float* __restrict__ W2a_w, const float* __restrict__ W2a_b,
                       const float* __restrict__ V_w,  const float* __restrict__ V_b,
                       const float* __restrict__ Va_w, const float* __restrict__ Va_b,
                       unsigned short* __restrict__ w1c, unsigned short* __restrict__ w2c,
                       unsigned short* __restrict__ vc,
                       float* __restrict__ bias1, float* __restrict__ bias2,
                       float* __restrict__ biasv,
                       int* __restrict__ cursor, int* __restrict__ perm)
{
    const int tid = blockIdx.x * blockDim.x + threadIdx.x;
    const int nth = gridDim.x * blockDim.x;

    // ---- scatter: blocks 0..127, one 256-id slice each ----
    if (blockIdx.x < B_N / 256) {
        __shared__ int lh[NJ], lb[NJ];
        const int lt = threadIdx.x;
        const int s0 = blockIdx.x * 256;
        if (lt < NJ) lh[lt] = 0;
        __syncthreads();
        int id = ids[s0 + lt];
        int rank = atomicAdd(&lh[id], 1);
        __syncthreads();
        if (lt < NJ)
            lb[lt] = lh[lt] ? atomicAdd(&cursor[lt], lh[lt]) : 0;
        __syncthreads();
        int pos = lb[id] + rank;
        if (pos < CAPJ) perm[id * CAPJ + pos] = s0 + lt;
    }

    // ---- weight combine (grid-stride over all blocks) ----
    // w2c: 12*256*64 quads
    for (int q = tid; q < NJ * 256 * 64; q += nth) {
        int k4 = (q & 63) << 2, h = (q >> 6) & 255, jj = q >> 14;
        const float* a = &W2_w[h * 257 + k4];
        const float* b = &W2a_w[(jj * 256 + h) * 257 + k4];
        ushort4 o;
        o.x = f2bf(a[0] + b[0]); o.y = f2bf(a[1] + b[1]);
        o.z = f2bf(a[2] + b[2]); o.w = f2bf(a[3] + b[3]);
        *(ushort4*)&w2c[(size_t)q << 2] = o;
    }
    // w1c: 12*256*16 quads (k padded to 64)
    for (int q = tid; q < NJ * 256 * 16; q += nth) {
        int k4 = (q & 15) << 2, h = (q >> 4) & 255, jj = q >> 12;
        ushort4 o;
        float v[4];
#pragma unroll
        for (int e = 0; e < 4; ++e) {
            int k = k4 + e;
            v[e] = (k < D_IN) ? (W1_w[h * 36 + k] + W1a_w[(jj * 256 + h) * 36 + k]) : 0.f;
        }
        o.x = f2bf(v[0]); o.y = f2bf(v[1]); o.z = f2bf(v[2]); o.w = f2bf(v[3]);
        *(ushort4*)&w1c[(size_t)q << 2] = o;
    }
    // vc: 12*48*64 quads
    for (int q = tid; q < NJ * 48 * 64; q += nth) {
        int k4 = (q & 63) << 2, qo = (q >> 6) % 48, jj = q / (48 * 64);
        ushort4 o;
        if (qo < QO) {
            const float* a = &V_w[qo * 257 + k4];
            const float* b = &Va_w[(jj * QO + qo) * 257 + k4];
            o.x = f2bf(a[0] + b[0]); o.y = f2bf(a[1] + b[1]);
            o.z = f2bf(a[2] + b[2]); o.w = f2bf(a[3] + b[3]);
        } else {
            o.x = o.y = o.z = o.w = 0;
        }
        *(ushort4*)&vc[(size_t)q << 2] = o;
    }
    // biases (fold ones-column)
    for (int i = tid; i < NJ * 256; i += nth) {
        int h = i & 255, jj = i >> 8;
        bias1[i] = W1_w[h * 36 + 35] + W1a_w[(jj * 256 + h) * 36 + 35] + W1_b[h] + W1a_b[i];
        bias2[i] = W2_w[h * 257 + 256] + W2a_w[(jj * 256 + h) * 257 + 256] + W2_b[h] + W2a_b[i];
    }
    for (int i = tid; i < NJ * 48; i += nth) {
        int qo = i % 48, jj = i / 48;
        float v = 0.f;
        if (qo < QO) v = V_w[qo * 257 + 256] + Va_w[(jj * QO + qo) * 257 + 256]
                       + V_b[qo] + Va_b[jj * QO + qo];
        biasv[i] = v;
    }
}

// ---------------------------------------------------------------------------
// Kernel 2: fused MLP — r14 body (measured best, e2e 47.9): single z-buffer,
// 21.6 KB LDS -> whole live grid co-resident, 4 waves of 64 N-rows, 6
// barriers, depth-1 weight prefetch across each barrier, compact per-block
// tile dispatch from counts[12], m204 bijective XCD swizzle over nt.
// NEW (T5): s_setprio(1) around each MFMA cluster — co-resident independent
// blocks sit at different phases, so the CU scheduler can favor MFMA-issuing
// waves (m191-style +4-7%; null only for lockstep grids, m190).
// MFMA 16x16x32 bf16 layouts:
//   A: lane holds A[lane&15][(lane>>4)*8+e]      (weights = A, rows)
//   B: lane holds B[(lane>>4)*8+e][lane&15]      (samples = B, cols)
//   D: col=lane&15 (sample), row=(lane>>4)*4+r   (output row)
// ---------------------------------------------------------------------------
__global__ __launch_bounds__(256, 4) void k_main(
    const float* __restrict__ x, float* __restrict__ out,
    const int* __restrict__ perm, const int* __restrict__ counts,
    const unsigned short* __restrict__ w1c, const unsigned short* __restrict__ w2c,
    const unsigned short* __restrict__ vc,
    const float* __restrict__ bias1, const float* __restrict__ bias2,
    const float* __restrict__ biasv)
{
    __shared__ __align__(16) unsigned short s_z1[TILE][264];   // z1, then z2
    __shared__ __align__(16) union {
        unsigned short xb[TILE][72];   // bf16 input tile (dead after layer 1)
        float          lg[TILE][40];   // logits (born at heads)
    } s_u;
    __shared__ int s_rows[TILE];

    const int bid = blockIdx.x;

    // ---- compact tile map from counts (uniform scalar ops, no arrays) ----
    int nt = 0;
#pragma unroll
    for (int jj = 0; jj < NJ; ++jj) nt += (counts[jj] + 31) >> 5;
    if (bid >= nt) return;

    // m204 bijective XCD swizzle over the live-tile space.
    const int q8 = nt >> 3, r8 = nt & 7;
    const int xcd = bid & 7, idx = bid >> 3;
    const int lbid = (xcd < r8 ? xcd * (q8 + 1) : r8 * (q8 + 1) + (xcd - r8) * q8) + idx;

    int j = 0, tb_j = 0, cj = 0, pacc = 0;
#pragma unroll
    for (int jj = 0; jj < NJ; ++jj) {
        int c = counts[jj];
        if (lbid >= pacc) { j = jj; tb_j = pacc; cj = c; }   // last satisfied wins
        pacc += (c + 31) >> 5;
    }
    if (cj > CAPJ) cj = CAPJ;          // insurance vs perm region overflow
    const int ts = (lbid - tb_j) << 5; // tile start within judge region

    const int tid  = threadIdx.x;
    const int lane = tid & 63;
    const int wave = tid >> 6;
    const int l16  = lane & 15;
    const int lk   = lane >> 4;

    // ---- prefetch ALL of this wave's layer-1 A fragments (32 VGPR) ----
    const unsigned short* w1p = w1c + ((size_t)j << 14) + (size_t)(wave * 64) * 64;
    v8bf w1a0[4], w1a1[4];
#pragma unroll
    for (int t = 0; t < 4; ++t) {
        const unsigned short* rp = w1p + (t * 16 + l16) * 64;
        w1a0[t] = *(const v8bf*)&rp[lk * 8];
        w1a1[t] = *(const v8bf*)&rp[32 + lk * 8];
    }

    if (tid < TILE)
        s_rows[tid] = (ts + tid < cj) ? perm[j * CAPJ + ts + tid] : -1;
    for (int i = tid; i < TILE * 36; i += 256) ((unsigned int*)s_u.xb)[i] = 0u;
    __syncthreads();                                   // (a) rows+zero ready

    for (int i = tid; i < TILE * D_IN; i += 256) {
        int s = i / D_IN, k = i - s * D_IN;
        int r = s_rows[s];
        s_u.xb[s][k] = f2bf(r >= 0 ? x[(size_t)r * D_IN + k] : 0.f);
    }
    __syncthreads();                                   // (b) xb ready

    const f32x4 vz = {0.f, 0.f, 0.f, 0.f};

    // ---- layer 1: z1[s][h] = relu(W1c[h]·xb[s] + b1[h]), wave owns 64 h ----
    {
        v8bf b1[2][2];
#pragma unroll
        for (int mt = 0; mt < 2; ++mt) {
            b1[mt][0] = *(const v8bf*)&s_u.xb[mt * 16 + l16][lk * 8];
            b1[mt][1] = *(const v8bf*)&s_u.xb[mt * 16 + l16][32 + lk * 8];
        }
        f32x4 acc[4][2];
#pragma unroll
        for (int t = 0; t < 4; ++t) { acc[t][0] = vz; acc[t][1] = vz; }
        __builtin_amdgcn_s_setprio(1);
#pragma unroll
        for (int t = 0; t < 4; ++t) {
#pragma unroll
            for (int mt = 0; mt < 2; ++mt) {
                acc[t][mt] = __builtin_amdgcn_mfma_f32_16x16x32_bf16(w1a0[t], b1[mt][0], acc[t][mt], 0, 0, 0);
                acc[t][mt] = __builtin_amdgcn_mfma_f32_16x16x32_bf16(w1a1[t], b1[mt][1], acc[t][mt], 0, 0, 0);
            }
        }
        __builtin_amdgcn_s_setprio(0);
        // prefetch layer-2 hc=0 A fragments before the barrier (16 VGPR)
        const unsigned short* w2p = w2c + ((size_t)j << 16) + (size_t)(wave * 64) * 256;
        v8bf a2pre[4];
#pragma unroll
        for (int gt = 0; gt < 4; ++gt)
            a2pre[gt] = *(const v8bf*)&w2p[(gt * 16 + l16) * 256 + lk * 8];

#pragma unroll
        for (int t = 0; t < 4; ++t) {
            f32x4 bz = *(const f32x4*)&bias1[j * 256 + wave * 64 + t * 16 + lk * 4];
#pragma unroll
            for (int mt = 0; mt < 2; ++mt) {
                float v0 = acc[t][mt][0] + bz[0], v1 = acc[t][mt][1] + bz[1];
                float v2 = acc[t][mt][2] + bz[2], v3 = acc[t][mt][3] + bz[3];
                v0 = v0 > 0.f ? v0 : 0.f; v1 = v1 > 0.f ? v1 : 0.f;
                v2 = v2 > 0.f ? v2 : 0.f; v3 = v3 > 0.f ? v3 : 0.f;
                uint2 pk; pk.x = pack2(v0, v1); pk.y = pack2(v2, v3);
                *(uint2*)&s_z1[mt * 16 + l16][wave * 64 + t * 16 + lk * 4] = pk;
            }
        }
        __syncthreads();                               // (c) z1 ready

        // ---- layer 2: z2 = relu(z1 @ W2c^T + b2), wave owns 64 g-rows ----
        f32x4 acc2[4][2];
#pragma unroll
        for (int gt = 0; gt < 4; ++gt) { acc2[gt][0] = vz; acc2[gt][1] = vz; }
        __builtin_amdgcn_s_setprio(1);
        {   // hc = 0 (prefetched A)
            v8bf bb0 = *(const v8bf*)&s_z1[l16][lk * 8];
            v8bf bb1 = *(const v8bf*)&s_z1[16 + l16][lk * 8];
#pragma unroll
            for (int gt = 0; gt < 4; ++gt) {
                acc2[gt][0] = __builtin_amdgcn_mfma_f32_16x16x32_bf16(a2pre[gt], bb0, acc2[gt][0], 0, 0, 0);
                acc2[gt][1] = __builtin_amdgcn_mfma_f32_16x16x32_bf16(a2pre[gt], bb1, acc2[gt][1], 0, 0, 0);
            }
        }
#pragma unroll 2
        for (int hc = 1; hc < 8; ++hc) {
            v8bf bb0 = *(const v8bf*)&s_z1[l16][hc * 32 + lk * 8];
            v8bf bb1 = *(const v8bf*)&s_z1[16 + l16][hc * 32 + lk * 8];
#pragma unroll
            for (int gt = 0; gt < 4; ++gt) {
                v8bf a = *(const v8bf*)&w2p[(gt * 16 + l16) * 256 + hc * 32 + lk * 8];
                acc2[gt][0] = __builtin_amdgcn_mfma_f32_16x16x32_bf16(a, bb0, acc2[gt][0], 0, 0, 0);
                acc2[gt][1] = __builtin_amdgcn_mfma_f32_16x16x32_bf16(a, bb1, acc2[gt][1], 0, 0, 0);
            }
        }
        __builtin_amdgcn_s_setprio(0);
        // prefetch heads gc=0 A fragment (in flight across the next barrier)
        const unsigned short* vp = vc + (size_t)j * 12288 + (size_t)(wave * 16) * 256;
        v8bf a3pre;
        if (wave < 3) a3pre = *(const v8bf*)&vp[l16 * 256 + lk * 8];

        __syncthreads();                               // (d) z1 reads drained
#pragma unroll
        for (int gt = 0; gt < 4; ++gt) {
            f32x4 bz = *(const f32x4*)&bias2[j * 256 + wave * 64 + gt * 16 + lk * 4];
#pragma unroll
            for (int mt = 0; mt < 2; ++mt) {
                float v0 = acc2[gt][mt][0] + bz[0], v1 = acc2[gt][mt][1] + bz[1];
                float v2 = acc2[gt][mt][2] + bz[2], v3 = acc2[gt][mt][3] + bz[3];
                v0 = v0 > 0.f ? v0 : 0.f; v1 = v1 > 0.f ? v1 : 0.f;
                v2 = v2 > 0.f ? v2 : 0.f; v3 = v3 > 0.f ? v3 : 0.f;
                uint2 pk; pk.x = pack2(v0, v1); pk.y = pack2(v2, v3);
                *(uint2*)&s_z1[mt * 16 + l16][wave * 64 + gt * 16 + lk * 4] = pk;
            }
        }
        __syncthreads();                               // (e) z2 ready

        // ---- heads: logits[s][qo] = Vc[qo]·z2[s] + bv[qo]; waves 0..2 ----
        if (wave < 3) {
            f32x4 av[2] = {vz, vz};
            __builtin_amdgcn_s_setprio(1);
            {   // gc = 0 (prefetched A)
                v8bf bb0 = *(const v8bf*)&s_z1[l16][lk * 8];
                v8bf bb1 = *(const v8bf*)&s_z1[16 + l16][lk * 8];
                av[0] = __builtin_amdgcn_mfma_f32_16x16x32_bf16(a3pre, bb0, av[0], 0, 0, 0);
                av[1] = __builtin_amdgcn_mfma_f32_16x16x32_bf16(a3pre, bb1, av[1], 0, 0, 0);
            }
#pragma unroll 4
            for (int gc = 1; gc < 8; ++gc) {
                v8bf bb0 = *(const v8bf*)&s_z1[l16][gc * 32 + lk * 8];
                v8bf bb1 = *(const v8bf*)&s_z1[16 + l16][gc * 32 + lk * 8];
                v8bf a = *(const v8bf*)&vp[l16 * 256 + gc * 32 + lk * 8];
                av[0] = __builtin_amdgcn_mfma_f32_16x16x32_bf16(a, bb0, av[0], 0, 0, 0);
                av[1] = __builtin_amdgcn_mfma_f32_16x16x32_bf16(a, bb1, av[1], 0, 0, 0);
            }
            __builtin_amdgcn_s_setprio(0);
            int qb = wave * 16 + lk * 4;
            if (qb < 36) {   // rows >= 35 never read by softmax
                f32x4 bz = *(const f32x4*)&biasv[j * 48 + qb];
#pragma unroll
                for (int mt = 0; mt < 2; ++mt) {
                    f32x4 v = av[mt] + bz;
                    *(f32x4*)&s_u.lg[mt * 16 + l16][qb] = v;
                }
            }
        }
    }
    __syncthreads();                                   // (f) logits ready

    // ---- softmax over O=5 per (s,q), write out ----
    if (tid < TILE * NQ) {
        int s = tid / NQ, qq = tid - s * NQ;
        int r = s_rows[s];
        if (r >= 0) {
            float l[NO], mx = -1e30f;
#pragma unroll
            for (int o = 0; o < NO; ++o) {
                l[o] = s_u.lg[s][qq * NO + o];
                mx = l[o] > mx ? l[o] : mx;
            }
            float sum = 0.f, e[NO];
#pragma unroll
            for (int o = 0; o < NO; ++o) { e[o] = __expf(l[o] - mx); sum += e[o]; }
            float inv = 1.f / sum;
            float* op = out + (size_t)r * QO + qq * NO;
#pragma unroll
            for (int o = 0; o < NO; ++o) op[o] = e[o] * inv;
        }
    }
}

// ---------------------------------------------------------------------------
extern "C" void kernel_launch(void* const* d_in, const int* in_sizes, int n_in,
                              void* d_out, int out_size, void* d_ws, size_t ws_size,
                              hipStream_t stream)
{
    const float* x     = (const float*)d_in[0];
    const int*   ids   = (const int*)d_in[1];
    const float* W1_w  = (const float*)d_in[2];
    const float* W1_b  = (const float*)d_in[3];
    const float* W2_w  = (const float*)d_in[4];
    const float* W2_b  = (const float*)d_in[5];
    const float* W1a_w = (const float*)d_in[6];
    const float* W1a_b = (const float*)d_in[7];
    const float* W2a_w = (const float*)d_in[8];
    const float* W2a_b = (const float*)d_in[9];
    const float* V_w   = (const float*)d_in[10];
    const float* V_b   = (const float*)d_in[11];
    const float* Va_w  = (const float*)d_in[12];
    const float* Va_b  = (const float*)d_in[13];
    float* out = (float*)d_out;

    char* ws = (char*)d_ws;
    size_t off = 0;
    auto take = [&](size_t nbytes) -> void* {
        void* p = ws + off;
        off = (off + nbytes + 255) & ~(size_t)255;
        return p;
    };
    unsigned short* w1c = (unsigned short*)take((size_t)NJ * 256 * 64 * 2);
    unsigned short* w2c = (unsigned short*)take((size_t)NJ * 256 * 256 * 2);
    unsigned short* vc  = (unsigned short*)take((size_t)NJ * 48 * 256 * 2);
    float* bias1        = (float*)take((size_t)NJ * 256 * 4);
    float* bias2        = (float*)take((size_t)NJ * 256 * 4);
    float* biasv        = (float*)take((size_t)NJ * 48 * 4);
    int* cursor         = (int*)take(NJ * 4);
    int* perm           = (int*)take((size_t)NJ * CAPJ * 4);

    hipMemsetAsync(cursor, 0, NJ * sizeof(int), stream);   // 48 B, trivial
    k_prep<<<768, 256, 0, stream>>>(ids, W1_w, W1_b, W2_w, W2_b, W1a_w, W1a_b,
                                    W2a_w, W2a_b, V_w, V_b, Va_w, Va_b,
                                    w1c, w2c, vc, bias1, bias2, biasv,
                                    cursor, perm);
    k_main<<<MAXT, 256, 0, stream>>>(x, out, perm, cursor,
                                     w1c, w2c, vc, bias1, bias2, biasv);
}